// Round 2
// baseline (1564.073 us; speedup 1.0000x reference)
//
#include <hip/hip_runtime.h>
#include <hip/hip_bf16.h>

#define Bb 4
#define Nn 1024
#define NHEAD 8
#define Dd 32
#define Cc 768
#define Ll 4
#define NT 512
#define NK 16

#define OFF_H 1048576
#define OFF_A 34603008

__device__ __forceinline__ float wred_max(float v){
  v = fmaxf(v, __shfl_xor(v, 8));
  v = fmaxf(v, __shfl_xor(v, 16));
  v = fmaxf(v, __shfl_xor(v, 32));
  return v;
}
__device__ __forceinline__ float wred_sum(float v){
  v += __shfl_xor(v, 8);
  v += __shfl_xor(v, 16);
  v += __shfl_xor(v, 32);
  return v;
}

__global__ __launch_bounds__(NT, 2) void egt_fused(
    const float* __restrict__ QKV, const float* __restrict__ E,
    const float* __restrict__ G, float* __restrict__ out)
{
  __shared__ float4 q4[NHEAD][33];   // [h][d] -> {Q[l0..l3]}  (pad to kill bank conflicts)
  __shared__ float4 atile[NT];       // [mg*8+h] -> {a for l0..3}
  __shared__ float  red[8][NHEAD][Ll];

  const int t  = threadIdx.x;
  const int h  = t & 7;
  const int mg = t >> 3;             // 0..63
  const int b  = blockIdx.x >> 8;    // 256 blocks per batch
  const int l0 = (blockIdx.x & 255) << 2;

  // ---- load Q transposed into LDS: q4[h][d].l = Q[l][d*8+h] ----
  for (int idx = t; idx < Ll * 256; idx += NT){
    int l = idx >> 8, dh = idx & 255;
    int d = dh >> 3, hq = dh & 7;
    ((float*)&q4[hq][d])[l] = QKV[(size_t)(b * Nn + l0 + l) * Cc + dh];
  }
  __syncthreads();

  float s[Ll][NK];
  float mx[Ll] = {-1e30f, -1e30f, -1e30f, -1e30f};

  int ebase[Ll];
  #pragma unroll
  for (int l = 0; l < Ll; l++) ebase[l] = (b * Nn + l0 + l) * (Nn * NHEAD);

  // ---- phase 1: scores = clip(QK^T) + E, write H_hat, online max ----
  #pragma unroll
  for (int k = 0; k < NK; k++){
    const int m = mg + (k << 6);
    const float* kp = QKV + (size_t)(b * Nn + m) * Cc + 256 + h;
    float kreg[Dd];
    #pragma unroll
    for (int d = 0; d < Dd; d++) kreg[d] = kp[d << 3];
    float a0 = 0.f, a1 = 0.f, a2 = 0.f, a3 = 0.f;
    #pragma unroll
    for (int d = 0; d < Dd; d++){
      float4 qv = q4[h][d];
      a0 = fmaf(kreg[d], qv.x, a0);
      a1 = fmaf(kreg[d], qv.y, a1);
      a2 = fmaf(kreg[d], qv.z, a2);
      a3 = fmaf(kreg[d], qv.w, a3);
    }
    float acc[Ll] = {a0, a1, a2, a3};
    #pragma unroll
    for (int l = 0; l < Ll; l++){
      int idx = ebase[l] + (k << 9) + t;
      float v = fminf(fmaxf(acc[l], -5.f), 5.f) + E[idx];
      s[l][k] = v;
      mx[l] = fmaxf(mx[l], v);
      out[OFF_H + idx] = v;
    }
  }

  // ---- reduce max over mg (64 groups = 8 per wave x 8 waves) ----
  const int w = t >> 6;
  #pragma unroll
  for (int l = 0; l < Ll; l++) mx[l] = wred_max(mx[l]);
  if ((t & 63) < 8){
    #pragma unroll
    for (int l = 0; l < Ll; l++) red[w][h][l] = mx[l];
  }
  __syncthreads();
  #pragma unroll
  for (int ww = 0; ww < 8; ww++){
    #pragma unroll
    for (int l = 0; l < Ll; l++) mx[l] = fmaxf(mx[l], red[ww][h][l]);
  }
  __syncthreads();

  // ---- exp + sum ----
  float sm[Ll] = {0.f, 0.f, 0.f, 0.f};
  #pragma unroll
  for (int k = 0; k < NK; k++){
    #pragma unroll
    for (int l = 0; l < Ll; l++){
      float p = __expf(s[l][k] - mx[l]);
      s[l][k] = p;
      sm[l] += p;
    }
  }
  #pragma unroll
  for (int l = 0; l < Ll; l++) sm[l] = wred_sum(sm[l]);
  if ((t & 63) < 8){
    #pragma unroll
    for (int l = 0; l < Ll; l++) red[w][h][l] = sm[l];
  }
  __syncthreads();
  float rcp[Ll];
  #pragma unroll
  for (int l = 0; l < Ll; l++){
    float tot = 0.f;
    #pragma unroll
    for (int ww = 0; ww < 8; ww++) tot += red[ww][h][l];
    rcp[l] = 1.f / tot;
  }
  __syncthreads();

  // ---- phase 2: A_tild + degrees + PV ----
  float vacc[Ll] = {0.f, 0.f, 0.f, 0.f};
  float dg[Ll]   = {0.f, 0.f, 0.f, 0.f};
  const int hh = t & 7;
  const int dd = (t >> 3) & 31;
  const int ms = t >> 8;

  #pragma unroll
  for (int k = 0; k < NK; k++){
    float4 av;
    #pragma unroll
    for (int l = 0; l < Ll; l++){
      int idx = ebase[l] + (k << 9) + t;
      float g = G[idx];
      float sig = 1.f / (1.f + __expf(-g));
      float a = s[l][k] * rcp[l] * sig;
      dg[l] += sig;
      ((float*)&av)[l] = a;
      out[OFF_A + idx] = a;
    }
    atile[t] = av;     // t == mg*8+h
    __syncthreads();
    #pragma unroll
    for (int mm = 0; mm < 32; mm++){
      int mgi = (ms << 5) + mm;
      int m = mgi + (k << 6);
      float v = QKV[(size_t)(b * Nn + m) * Cc + 512 + (dd << 3) + hh];
      float4 a4 = atile[(mgi << 3) + hh];
      vacc[0] = fmaf(a4.x, v, vacc[0]);
      vacc[1] = fmaf(a4.y, v, vacc[1]);
      vacc[2] = fmaf(a4.z, v, vacc[2]);
      vacc[3] = fmaf(a4.w, v, vacc[3]);
    }
    __syncthreads();
  }

  // ---- degrees reduce -> log1p scalers ----
  #pragma unroll
  for (int l = 0; l < Ll; l++) dg[l] = wred_sum(dg[l]);
  if ((t & 63) < 8){
    #pragma unroll
    for (int l = 0; l < Ll; l++) red[w][h][l] = dg[l];
  }
  __syncthreads();
  float scaler[Ll];
  #pragma unroll
  for (int l = 0; l < Ll; l++){
    float tot = 0.f;
    #pragma unroll
    for (int ww = 0; ww < 8; ww++) tot += red[ww][h][l];
    scaler[l] = log1pf(tot);
  }

  // ---- combine ms halves and write V_att ----
  if (ms == 1) atile[t - 256] = make_float4(vacc[0], vacc[1], vacc[2], vacc[3]);
  __syncthreads();
  if (ms == 0){
    float4 o = atile[t];
    float ovals[Ll] = {o.x, o.y, o.z, o.w};
    #pragma unroll
    for (int l = 0; l < Ll; l++){
      float vtot = vacc[l] + ovals[l];
      int oidx = (b * Nn + l0 + l) * (Dd * NHEAD) + (dd << 3) + hh;
      out[oidx] = vtot * scaler[l];
    }
  }
}

extern "C" void kernel_launch(void* const* d_in, const int* in_sizes, int n_in,
                              void* d_out, int out_size, void* d_ws, size_t ws_size,
                              hipStream_t stream) {
  const float* QKV = (const float*)d_in[0];
  const float* E   = (const float*)d_in[1];
  const float* G   = (const float*)d_in[2];
  float* out = (float*)d_out;
  dim3 grid(Bb * (Nn / Ll));   // 1024 blocks
  egt_fused<<<grid, NT, 0, stream>>>(QKV, E, G, out);
}

// Round 4
// 623.672 us; speedup vs baseline: 2.5078x; 2.5078x over previous
//
#include <hip/hip_runtime.h>

#define NHEAD 8
#define NT 512
#define KT 32
#define NTILE 32
#define RS 164          // h2 (dword) stride per m-row in kv tile (8*20+4 pad)
#define OFF_H 1048576
#define OFF_A 34603008

typedef __fp16 h2 __attribute__((ext_vector_type(2)));
typedef __fp16 h4 __attribute__((ext_vector_type(4)));
typedef __fp16 h8 __attribute__((ext_vector_type(8)));

__device__ __forceinline__ float dot2f(h2 a, h2 b, float c){
#if __has_builtin(__builtin_amdgcn_fdot2)
  return __builtin_amdgcn_fdot2(a, b, c, false);
#else
  return fmaf((float)a[0], (float)b[0], fmaf((float)a[1], (float)b[1], c));
#endif
}

__device__ __forceinline__ void stage_issue(const float* __restrict__ QKV, size_t qkvbase,
                                            int ktile, int off, int srow, int shs, int sjp,
                                            float4 sf[4]){
  const float* src = QKV + qkvbase + (size_t)(ktile*KT + srow)*768 + off + sjp*32 + shs*4;
  #pragma unroll
  for (int dd = 0; dd < 4; dd++) sf[dd] = *(const float4*)(src + dd*8);
}

__device__ __forceinline__ void stage_write(h2* kvb, int buf, int srow, int shs, int sjp,
                                            const float4 sf[4]){
  #pragma unroll
  for (int hh = 0; hh < 4; hh++){
    h2 lo = __builtin_amdgcn_cvt_pkrtz(((const float*)&sf[0])[hh], ((const float*)&sf[1])[hh]);
    h2 hi = __builtin_amdgcn_cvt_pkrtz(((const float*)&sf[2])[hh], ((const float*)&sf[3])[hh]);
    h4 pk; pk[0]=lo[0]; pk[1]=lo[1]; pk[2]=hi[0]; pk[3]=hi[1];
    *(h4*)&kvb[(buf*KT + srow)*RS + (4*shs+hh)*20 + 2*sjp] = pk;
  }
}

__global__ __launch_bounds__(NT, 4) void egt_fused(
    const float* __restrict__ QKV, const float* __restrict__ E,
    const float* __restrict__ G, float* __restrict__ out)
{
  __shared__ __align__(16) h2 kvb[2*KT*RS];   // K tiles (phase1) / V tiles (phase2), dbuf
  __shared__ __align__(16) h2 at[KT][9][2];   // A fragments, padded
  __shared__ float red[8][2][NHEAD][2];
  __shared__ float fin[4][NHEAD];

  const int t   = threadIdx.x;
  const int h   = t & 7;
  const int lh  = (t >> 3) & 1;
  const int mg2 = t >> 4;          // 0..31  (mapping-1: scores/E/G/A io)
  const int w   = t >> 6;
  const int srow = t >> 4;         // staging decode
  const int shs  = (t >> 3) & 1;
  const int sjp  = t & 7;
  const int pmq = t & 7;           // PV decode
  const int pdq = (t >> 3) & 7;
  const int ph  = t >> 6;
  const int b  = blockIdx.x >> 8;
  const int l0 = (blockIdx.x & 255) << 2;
  const size_t qkvbase = (size_t)(b * 1024) * 768;

  const int ebase0 = (b*1024 + l0 + 2*lh) * 8192;
  const int ebase1 = ebase0 + 8192;

  // ---- pack Q into registers (fp16 pairs over d) ----
  h2 q0[16], q1[16];
  {
    const float* qp0 = QKV + qkvbase + (size_t)(l0 + 2*lh) * 768 + h;
    const float* qp1 = qp0 + 768;
    #pragma unroll
    for (int jd = 0; jd < 16; jd++){
      q0[jd] = __builtin_amdgcn_cvt_pkrtz(qp0[jd*16], qp0[jd*16 + 8]);
      q1[jd] = __builtin_amdgcn_cvt_pkrtz(qp1[jd*16], qp1[jd*16 + 8]);
    }
  }

  // ---- phase-1 prologue: stage K(0), prefetch E(0) ----
  float e0, e1;
  {
    float4 sf[4];
    stage_issue(QKV, qkvbase, 0, 256, srow, shs, sjp, sf);
    e0 = E[ebase0 + mg2*8 + h];
    e1 = E[ebase1 + mg2*8 + h];
    stage_write(kvb, 0, srow, shs, sjp, sf);
  }
  __syncthreads();

  h2 s2[NTILE];
  float mx0 = -1e30f, mx1 = -1e30f;

  // ---- phase 1: H_hat = clip(QK^T)+E, keep scores in regs ----
  #pragma unroll
  for (int k = 0; k < NTILE; k++){
    const int cur = k & 1;
    float4 sn[4]; float en0, en1;
    if (k < NTILE-1){
      stage_issue(QKV, qkvbase, k+1, 256, srow, shs, sjp, sn);
      en0 = E[ebase0 + ((k+1)*KT + mg2)*8 + h];
      en1 = E[ebase1 + ((k+1)*KT + mg2)*8 + h];
    }
    float acc0 = 0.f, acc1 = 0.f;
    const h2* kr = &kvb[(cur*KT + mg2)*RS + h*20];
    #pragma unroll
    for (int jw = 0; jw < 4; jw++){
      h8 kk = *(const h8*)&kr[jw*4];
      #pragma unroll
      for (int u = 0; u < 4; u++){
        h2 kj; kj[0] = kk[2*u]; kj[1] = kk[2*u+1];
        acc0 = dot2f(q0[jw*4+u], kj, acc0);
        acc1 = dot2f(q1[jw*4+u], kj, acc1);
      }
    }
    float h0 = fminf(fmaxf(acc0, -5.f), 5.f) + e0;
    float h1 = fminf(fmaxf(acc1, -5.f), 5.f) + e1;
    out[OFF_H + ebase0 + (k*KT + mg2)*8 + h] = h0;
    out[OFF_H + ebase1 + (k*KT + mg2)*8 + h] = h1;
    s2[k] = __builtin_amdgcn_cvt_pkrtz(h0, h1);
    mx0 = fmaxf(mx0, h0); mx1 = fmaxf(mx1, h1);
    if (k < NTILE-1){
      stage_write(kvb, (k+1)&1, srow, shs, sjp, sn);
      e0 = en0; e1 = en1;
    }
    __syncthreads();
  }

  // ---- max reduce over m ----
  mx0 = fmaxf(mx0, __shfl_xor(mx0, 16)); mx0 = fmaxf(mx0, __shfl_xor(mx0, 32));
  mx1 = fmaxf(mx1, __shfl_xor(mx1, 16)); mx1 = fmaxf(mx1, __shfl_xor(mx1, 32));
  if (((t >> 4) & 3) == 0){ red[w][lh][h][0] = mx0; red[w][lh][h][1] = mx1; }
  __syncthreads();
  #pragma unroll
  for (int ww = 0; ww < 8; ww++){
    mx0 = fmaxf(mx0, red[ww][lh][h][0]);
    mx1 = fmaxf(mx1, red[ww][lh][h][1]);
  }
  __syncthreads();

  // ---- exp-sum reduce ----
  float sm0 = 0.f, sm1 = 0.f;
  #pragma unroll
  for (int k = 0; k < NTILE; k++){
    sm0 += __expf((float)s2[k][0] - mx0);
    sm1 += __expf((float)s2[k][1] - mx1);
  }
  sm0 += __shfl_xor(sm0, 16); sm0 += __shfl_xor(sm0, 32);
  sm1 += __shfl_xor(sm1, 16); sm1 += __shfl_xor(sm1, 32);
  if (((t >> 4) & 3) == 0){ red[w][lh][h][0] = sm0; red[w][lh][h][1] = sm1; }
  __syncthreads();
  float tot0 = 0.f, tot1 = 0.f;
  #pragma unroll
  for (int ww = 0; ww < 8; ww++){ tot0 += red[ww][lh][h][0]; tot1 += red[ww][lh][h][1]; }
  const float rcp0 = 1.f / tot0, rcp1 = 1.f / tot1;
  __syncthreads();

  // ---- phase-2 prologue: stage V(0), prefetch G(0) ----
  float g0, g1;
  {
    float4 sf[4];
    stage_issue(QKV, qkvbase, 0, 512, srow, shs, sjp, sf);
    g0 = G[ebase0 + mg2*8 + h];
    g1 = G[ebase1 + mg2*8 + h];
    stage_write(kvb, 0, srow, shs, sjp, sf);
  }
  __syncthreads();

  float vacc[4][4] = {{0.f,0.f,0.f,0.f},{0.f,0.f,0.f,0.f},{0.f,0.f,0.f,0.f},{0.f,0.f,0.f,0.f}};
  float dg0 = 0.f, dg1 = 0.f;

  // ---- phase 2: A_tild + degrees + PV ----
  #pragma unroll
  for (int k = 0; k < NTILE; k++){
    const int cur = k & 1;
    float4 sn[4]; float gn0, gn1;
    if (k < NTILE-1){
      stage_issue(QKV, qkvbase, k+1, 512, srow, shs, sjp, sn);
      gn0 = G[ebase0 + ((k+1)*KT + mg2)*8 + h];
      gn1 = G[ebase1 + ((k+1)*KT + mg2)*8 + h];
    }
    // A-step (mapping-1)
    float sig0 = 1.f / (1.f + __expf(-g0));
    float sig1 = 1.f / (1.f + __expf(-g1));
    float A0 = __expf((float)s2[k][0] - mx0) * rcp0 * sig0;
    float A1 = __expf((float)s2[k][1] - mx1) * rcp1 * sig1;
    dg0 += sig0; dg1 += sig1;
    out[OFF_A + ebase0 + (k*KT + mg2)*8 + h] = A0;
    out[OFF_A + ebase1 + (k*KT + mg2)*8 + h] = A1;
    at[mg2][h][lh] = __builtin_amdgcn_cvt_pkrtz(A0, A1);
    __syncthreads();
    // PV (mapping-2)
    #pragma unroll
    for (int i = 0; i < 4; i++){
      const int mm = pmq + 8*i;
      h4 vv = *(const h4*)&kvb[(cur*KT + mm)*RS + ph*20 + 2*pdq];
      h4 aa = *(const h4*)&at[mm][ph][0];
      float vf0 = (float)vv[0], vf1 = (float)vv[1], vf2 = (float)vv[2], vf3 = (float)vv[3];
      float a0 = (float)aa[0], a1 = (float)aa[1], a2 = (float)aa[2], a3 = (float)aa[3];
      vacc[0][0] = fmaf(a0, vf0, vacc[0][0]); vacc[0][1] = fmaf(a0, vf1, vacc[0][1]);
      vacc[0][2] = fmaf(a0, vf2, vacc[0][2]); vacc[0][3] = fmaf(a0, vf3, vacc[0][3]);
      vacc[1][0] = fmaf(a1, vf0, vacc[1][0]); vacc[1][1] = fmaf(a1, vf1, vacc[1][1]);
      vacc[1][2] = fmaf(a1, vf2, vacc[1][2]); vacc[1][3] = fmaf(a1, vf3, vacc[1][3]);
      vacc[2][0] = fmaf(a2, vf0, vacc[2][0]); vacc[2][1] = fmaf(a2, vf1, vacc[2][1]);
      vacc[2][2] = fmaf(a2, vf2, vacc[2][2]); vacc[2][3] = fmaf(a2, vf3, vacc[2][3]);
      vacc[3][0] = fmaf(a3, vf0, vacc[3][0]); vacc[3][1] = fmaf(a3, vf1, vacc[3][1]);
      vacc[3][2] = fmaf(a3, vf2, vacc[3][2]); vacc[3][3] = fmaf(a3, vf3, vacc[3][3]);
    }
    if (k < NTILE-1){
      stage_write(kvb, (k+1)&1, srow, shs, sjp, sn);
      g0 = gn0; g1 = gn1;
    }
    __syncthreads();
  }

  // ---- degrees -> log1p scalers ----
  dg0 += __shfl_xor(dg0, 16); dg0 += __shfl_xor(dg0, 32);
  dg1 += __shfl_xor(dg1, 16); dg1 += __shfl_xor(dg1, 32);
  if (((t >> 4) & 3) == 0){ red[w][lh][h][0] = dg0; red[w][lh][h][1] = dg1; }
  __syncthreads();
  if (t < 16){
    float td0 = 0.f, td1 = 0.f;
    #pragma unroll
    for (int ww = 0; ww < 8; ww++){ td0 += red[ww][lh][h][0]; td1 += red[ww][lh][h][1]; }
    fin[2*lh + 0][h] = log1pf(td0);
    fin[2*lh + 1][h] = log1pf(td1);
  }
  __syncthreads();

  // ---- reduce PV over m-slices, write V_att ----
  #pragma unroll
  for (int l = 0; l < 4; l++){
    #pragma unroll
    for (int di = 0; di < 4; di++){
      float v = vacc[l][di];
      v += __shfl_xor(v, 1); v += __shfl_xor(v, 2); v += __shfl_xor(v, 4);
      vacc[l][di] = v;
    }
  }
  if (pmq == 0){
    float sc0 = fin[0][ph], sc1 = fin[1][ph], sc2 = fin[2][ph], sc3 = fin[3][ph];
    const int obase = (b*1024 + l0) * 256;
    #pragma unroll
    for (int di = 0; di < 4; di++){
      const int c = (pdq*4 + di)*8 + ph;
      out[obase +   0 + c] = vacc[0][di] * sc0;
      out[obase + 256 + c] = vacc[1][di] * sc1;
      out[obase + 512 + c] = vacc[2][di] * sc2;
      out[obase + 768 + c] = vacc[3][di] * sc3;
    }
  }
}

extern "C" void kernel_launch(void* const* d_in, const int* in_sizes, int n_in,
                              void* d_out, int out_size, void* d_ws, size_t ws_size,
                              hipStream_t stream) {
  const float* QKV = (const float*)d_in[0];
  const float* E   = (const float*)d_in[1];
  const float* G   = (const float*)d_in[2];
  float* out = (float*)d_out;
  dim3 grid(1024);
  egt_fused<<<grid, NT, 0, stream>>>(QKV, E, G, out);
}

// Round 5
// 523.674 us; speedup vs baseline: 2.9867x; 1.1910x over previous
//
#include <hip/hip_runtime.h>

#define NHEAD 8
#define NT 512
#define KT 32
#define NTILE 32
#define RS 164          // h2 (dword) stride per m-row in kv tile (8*20+4 pad)
#define OFF_H 1048576
#define OFF_A 34603008

typedef __fp16 h2 __attribute__((ext_vector_type(2)));
typedef __fp16 h4 __attribute__((ext_vector_type(4)));
typedef __fp16 h8 __attribute__((ext_vector_type(8)));

__device__ __forceinline__ float dot2f(h2 a, h2 b, float c){
#if __has_builtin(__builtin_amdgcn_fdot2)
  return __builtin_amdgcn_fdot2(a, b, c, false);
#else
  return fmaf((float)a[0], (float)b[0], fmaf((float)a[1], (float)b[1], c));
#endif
}

__device__ __forceinline__ void stage_issue(const float* __restrict__ QKV, size_t qkvbase,
                                            int ktile, int off, int srow, int shs, int sjp,
                                            float4 sf[4]){
  const float* src = QKV + qkvbase + (size_t)(ktile*KT + srow)*768 + off + sjp*32 + shs*4;
  #pragma unroll
  for (int dd = 0; dd < 4; dd++) sf[dd] = *(const float4*)(src + dd*8);
}

__device__ __forceinline__ void stage_write(h2* kvb, int buf, int srow, int shs, int sjp,
                                            const float4 sf[4]){
  #pragma unroll
  for (int hh = 0; hh < 4; hh++){
    h2 lo = __builtin_amdgcn_cvt_pkrtz(((const float*)&sf[0])[hh], ((const float*)&sf[1])[hh]);
    h2 hi = __builtin_amdgcn_cvt_pkrtz(((const float*)&sf[2])[hh], ((const float*)&sf[3])[hh]);
    h4 pk; pk[0]=lo[0]; pk[1]=lo[1]; pk[2]=hi[0]; pk[3]=hi[1];
    *(h4*)&kvb[(buf*KT + srow)*RS + (4*shs+hh)*20 + 2*sjp] = pk;
  }
}

__global__ __launch_bounds__(NT, 2) void egt_fused(
    const float* __restrict__ QKV, const float* __restrict__ E,
    const float* __restrict__ G, float* __restrict__ out)
{
  __shared__ __align__(16) h2 kvb[2*KT*RS];    // K tiles (phase1) / V tiles (phase2), dbuf
  __shared__ __align__(16) float at[KT][9][4]; // A fragments (fp32), padded rows
  __shared__ float red[8][2][NHEAD][2];
  __shared__ float fin[4][NHEAD];

  const int t   = threadIdx.x;
  const int h   = t & 7;
  const int lh  = (t >> 3) & 1;
  const int mg2 = t >> 4;          // 0..31  (mapping-1: scores/E/G/A io)
  const int w   = t >> 6;
  const int srow = t >> 4;         // staging decode
  const int shs  = (t >> 3) & 1;
  const int sjp  = t & 7;
  const int pmq = t & 7;           // PV decode
  const int pdq = (t >> 3) & 7;
  const int ph  = t >> 6;
  const int b  = blockIdx.x >> 8;
  const int l0 = (blockIdx.x & 255) << 2;
  const size_t qkvbase = (size_t)(b * 1024) * 768;

  const int ebase0 = (b*1024 + l0 + 2*lh) * 8192;
  const int ebase1 = ebase0 + 8192;

  // ---- pack Q into registers (fp16 pairs over d) ----
  h2 q0[16], q1[16];
  {
    const float* qp0 = QKV + qkvbase + (size_t)(l0 + 2*lh) * 768 + h;
    const float* qp1 = qp0 + 768;
    #pragma unroll
    for (int jd = 0; jd < 16; jd++){
      q0[jd] = __builtin_amdgcn_cvt_pkrtz(qp0[jd*16], qp0[jd*16 + 8]);
      q1[jd] = __builtin_amdgcn_cvt_pkrtz(qp1[jd*16], qp1[jd*16 + 8]);
    }
  }

  // ---- phase-1 prologue: stage K(0), prefetch E(0) ----
  float e0, e1;
  {
    float4 sf[4];
    stage_issue(QKV, qkvbase, 0, 256, srow, shs, sjp, sf);
    e0 = E[ebase0 + mg2*8 + h];
    e1 = E[ebase1 + mg2*8 + h];
    stage_write(kvb, 0, srow, shs, sjp, sf);
  }
  __syncthreads();

  h2 s2[NTILE];
  float mx0 = -1e30f, mx1 = -1e30f;

  // ---- phase 1: H_hat = clip(QK^T)+E, keep scores in regs ----
  #pragma unroll
  for (int k = 0; k < NTILE; k++){
    const int cur = k & 1;
    float4 sn[4]; float en0, en1;
    if (k < NTILE-1){
      stage_issue(QKV, qkvbase, k+1, 256, srow, shs, sjp, sn);
      en0 = E[ebase0 + ((k+1)*KT + mg2)*8 + h];
      en1 = E[ebase1 + ((k+1)*KT + mg2)*8 + h];
    }
    float acc0 = 0.f, acc1 = 0.f;
    const h2* kr = &kvb[(cur*KT + mg2)*RS + h*20];
    #pragma unroll
    for (int jw = 0; jw < 4; jw++){
      h8 kk = *(const h8*)&kr[jw*4];
      #pragma unroll
      for (int u = 0; u < 4; u++){
        h2 kj; kj[0] = kk[2*u]; kj[1] = kk[2*u+1];
        acc0 = dot2f(q0[jw*4+u], kj, acc0);
        acc1 = dot2f(q1[jw*4+u], kj, acc1);
      }
    }
    float h0 = fminf(fmaxf(acc0, -5.f), 5.f) + e0;
    float h1 = fminf(fmaxf(acc1, -5.f), 5.f) + e1;
    out[OFF_H + ebase0 + (k*KT + mg2)*8 + h] = h0;
    out[OFF_H + ebase1 + (k*KT + mg2)*8 + h] = h1;
    s2[k] = __builtin_amdgcn_cvt_pkrtz(h0, h1);
    mx0 = fmaxf(mx0, h0); mx1 = fmaxf(mx1, h1);
    if (k < NTILE-1){
      stage_write(kvb, (k+1)&1, srow, shs, sjp, sn);
      e0 = en0; e1 = en1;
    }
    __syncthreads();
  }

  // ---- max reduce over m ----
  mx0 = fmaxf(mx0, __shfl_xor(mx0, 16)); mx0 = fmaxf(mx0, __shfl_xor(mx0, 32));
  mx1 = fmaxf(mx1, __shfl_xor(mx1, 16)); mx1 = fmaxf(mx1, __shfl_xor(mx1, 32));
  if (((t >> 4) & 3) == 0){ red[w][lh][h][0] = mx0; red[w][lh][h][1] = mx1; }
  __syncthreads();
  #pragma unroll
  for (int ww = 0; ww < 8; ww++){
    mx0 = fmaxf(mx0, red[ww][lh][h][0]);
    mx1 = fmaxf(mx1, red[ww][lh][h][1]);
  }
  __syncthreads();

  // ---- exp-sum reduce ----
  float sm0 = 0.f, sm1 = 0.f;
  #pragma unroll
  for (int k = 0; k < NTILE; k++){
    sm0 += __expf((float)s2[k][0] - mx0);
    sm1 += __expf((float)s2[k][1] - mx1);
  }
  sm0 += __shfl_xor(sm0, 16); sm0 += __shfl_xor(sm0, 32);
  sm1 += __shfl_xor(sm1, 16); sm1 += __shfl_xor(sm1, 32);
  if (((t >> 4) & 3) == 0){ red[w][lh][h][0] = sm0; red[w][lh][h][1] = sm1; }
  __syncthreads();
  float tot0 = 0.f, tot1 = 0.f;
  #pragma unroll
  for (int ww = 0; ww < 8; ww++){ tot0 += red[ww][lh][h][0]; tot1 += red[ww][lh][h][1]; }
  const float rcp0 = 1.f / tot0, rcp1 = 1.f / tot1;
  __syncthreads();

  // ---- phase-2 prologue: stage V(0), prefetch G(0) ----
  float g0, g1;
  {
    float4 sf[4];
    stage_issue(QKV, qkvbase, 0, 512, srow, shs, sjp, sf);
    g0 = G[ebase0 + mg2*8 + h];
    g1 = G[ebase1 + mg2*8 + h];
    stage_write(kvb, 0, srow, shs, sjp, sf);
  }
  __syncthreads();

  float vacc[4][4] = {{0.f,0.f,0.f,0.f},{0.f,0.f,0.f,0.f},{0.f,0.f,0.f,0.f},{0.f,0.f,0.f,0.f}};
  float dg0 = 0.f, dg1 = 0.f;

  // ---- phase 2: A_tild + degrees + PV ----
  #pragma unroll
  for (int k = 0; k < NTILE; k++){
    const int cur = k & 1;
    float4 sn[4]; float gn0, gn1;
    if (k < NTILE-1){
      stage_issue(QKV, qkvbase, k+1, 512, srow, shs, sjp, sn);
      gn0 = G[ebase0 + ((k+1)*KT + mg2)*8 + h];
      gn1 = G[ebase1 + ((k+1)*KT + mg2)*8 + h];
    }
    // A-step (mapping-1)
    float sig0 = 1.f / (1.f + __expf(-g0));
    float sig1 = 1.f / (1.f + __expf(-g1));
    float A0 = __expf((float)s2[k][0] - mx0) * rcp0 * sig0;
    float A1 = __expf((float)s2[k][1] - mx1) * rcp1 * sig1;
    dg0 += sig0; dg1 += sig1;
    out[OFF_A + ebase0 + (k*KT + mg2)*8 + h] = A0;
    out[OFF_A + ebase1 + (k*KT + mg2)*8 + h] = A1;
    *(float2*)&at[mg2][h][2*lh] = make_float2(A0, A1);
    __syncthreads();
    // PV (mapping-2)
    #pragma unroll
    for (int i = 0; i < 4; i++){
      const int mm = pmq + 8*i;
      h4 vv = *(const h4*)&kvb[(cur*KT + mm)*RS + ph*20 + 2*pdq];
      float4 aa = *(const float4*)&at[mm][ph][0];
      float vf0 = (float)vv[0], vf1 = (float)vv[1], vf2 = (float)vv[2], vf3 = (float)vv[3];
      vacc[0][0] = fmaf(aa.x, vf0, vacc[0][0]); vacc[0][1] = fmaf(aa.x, vf1, vacc[0][1]);
      vacc[0][2] = fmaf(aa.x, vf2, vacc[0][2]); vacc[0][3] = fmaf(aa.x, vf3, vacc[0][3]);
      vacc[1][0] = fmaf(aa.y, vf0, vacc[1][0]); vacc[1][1] = fmaf(aa.y, vf1, vacc[1][1]);
      vacc[1][2] = fmaf(aa.y, vf2, vacc[1][2]); vacc[1][3] = fmaf(aa.y, vf3, vacc[1][3]);
      vacc[2][0] = fmaf(aa.z, vf0, vacc[2][0]); vacc[2][1] = fmaf(aa.z, vf1, vacc[2][1]);
      vacc[2][2] = fmaf(aa.z, vf2, vacc[2][2]); vacc[2][3] = fmaf(aa.z, vf3, vacc[2][3]);
      vacc[3][0] = fmaf(aa.w, vf0, vacc[3][0]); vacc[3][1] = fmaf(aa.w, vf1, vacc[3][1]);
      vacc[3][2] = fmaf(aa.w, vf2, vacc[3][2]); vacc[3][3] = fmaf(aa.w, vf3, vacc[3][3]);
    }
    if (k < NTILE-1){
      stage_write(kvb, (k+1)&1, srow, shs, sjp, sn);
      g0 = gn0; g1 = gn1;
    }
    __syncthreads();
  }

  // ---- degrees -> log1p scalers ----
  dg0 += __shfl_xor(dg0, 16); dg0 += __shfl_xor(dg0, 32);
  dg1 += __shfl_xor(dg1, 16); dg1 += __shfl_xor(dg1, 32);
  if (((t >> 4) & 3) == 0){ red[w][lh][h][0] = dg0; red[w][lh][h][1] = dg1; }
  __syncthreads();
  if (t < 16){
    float td0 = 0.f, td1 = 0.f;
    #pragma unroll
    for (int ww = 0; ww < 8; ww++){ td0 += red[ww][lh][h][0]; td1 += red[ww][lh][h][1]; }
    fin[2*lh + 0][h] = log1pf(td0);
    fin[2*lh + 1][h] = log1pf(td1);
  }
  __syncthreads();

  // ---- reduce PV over m-slices, write V_att ----
  #pragma unroll
  for (int l = 0; l < 4; l++){
    #pragma unroll
    for (int di = 0; di < 4; di++){
      float v = vacc[l][di];
      v += __shfl_xor(v, 1); v += __shfl_xor(v, 2); v += __shfl_xor(v, 4);
      vacc[l][di] = v;
    }
  }
  if (pmq == 0){
    float sc0 = fin[0][ph], sc1 = fin[1][ph], sc2 = fin[2][ph], sc3 = fin[3][ph];
    const int obase = (b*1024 + l0) * 256;
    #pragma unroll
    for (int di = 0; di < 4; di++){
      const int c = (pdq*4 + di)*8 + ph;
      out[obase +   0 + c] = vacc[0][di] * sc0;
      out[obase + 256 + c] = vacc[1][di] * sc1;
      out[obase + 512 + c] = vacc[2][di] * sc2;
      out[obase + 768 + c] = vacc[3][di] * sc3;
    }
  }
}

extern "C" void kernel_launch(void* const* d_in, const int* in_sizes, int n_in,
                              void* d_out, int out_size, void* d_ws, size_t ws_size,
                              hipStream_t stream) {
  const float* QKV = (const float*)d_in[0];
  const float* E   = (const float*)d_in[1];
  const float* G   = (const float*)d_in[2];
  float* out = (float*)d_out;
  dim3 grid(1024);
  egt_fused<<<grid, NT, 0, stream>>>(QKV, E, G, out);
}

// Round 6
// 408.653 us; speedup vs baseline: 3.8274x; 1.2815x over previous
//
#include <hip/hip_runtime.h>

#define NHEAD 8
#define NT 512
#define KT 32
#define NTILE 32
#define RS 166          // h2 (dword) stride per m-row in kv tile (8*20 + 6 pad)
#define OFF_H 1048576
#define OFF_A 34603008

typedef __fp16 h2 __attribute__((ext_vector_type(2)));
typedef __fp16 h4 __attribute__((ext_vector_type(4)));
typedef __fp16 h8 __attribute__((ext_vector_type(8)));

__device__ __forceinline__ float dot2f(h2 a, h2 b, float c){
#if __has_builtin(__builtin_amdgcn_fdot2)
  return __builtin_amdgcn_fdot2(a, b, c, false);
#else
  return fmaf((float)a[0], (float)b[0], fmaf((float)a[1], (float)b[1], c));
#endif
}

__device__ __forceinline__ void stage_issue(const float* __restrict__ QKV, size_t qkvbase,
                                            int ktile, int off, int srow, int shs, int sjp,
                                            float4 sf[4]){
  const float* src = QKV + qkvbase + (size_t)(ktile*KT + srow)*768 + off + sjp*32 + shs*4;
  #pragma unroll
  for (int dd = 0; dd < 4; dd++) sf[dd] = *(const float4*)(src + dd*8);
}

__device__ __forceinline__ void stage_write(h2* kvb, int slot, int srow, int shs, int sjp,
                                            const float4 sf[4]){
  #pragma unroll
  for (int hh = 0; hh < 4; hh++){
    h2 lo = __builtin_amdgcn_cvt_pkrtz(((const float*)&sf[0])[hh], ((const float*)&sf[1])[hh]);
    h2 hi = __builtin_amdgcn_cvt_pkrtz(((const float*)&sf[2])[hh], ((const float*)&sf[3])[hh]);
    h4 pk; pk[0]=lo[0]; pk[1]=lo[1]; pk[2]=hi[0]; pk[3]=hi[1];
    *(h4*)&kvb[(slot*KT + srow)*RS + (4*shs+hh)*20 + 2*sjp] = pk;
  }
}

__global__ __launch_bounds__(NT, 2) void egt_fused(
    const float* __restrict__ QKV, const float* __restrict__ E,
    const float* __restrict__ G, float* __restrict__ out)
{
  __shared__ __align__(16) h2 kvb[3*KT*RS];      // K/V ring, 3 slots
  __shared__ __align__(16) float at2[2][KT][9][4]; // A fragments, dbuf, padded rows
  __shared__ float red[8][2][NHEAD][2];
  __shared__ float fin[4][NHEAD];

  const int t   = threadIdx.x;
  const int h   = t & 7;
  const int lh  = (t >> 3) & 1;
  const int mg2 = t >> 4;          // 0..31  (mapping-1: scores/E/G/A io)
  const int w   = t >> 6;
  const int srow = t >> 4;         // staging decode
  const int shs  = (t >> 3) & 1;
  const int sjp  = t & 7;
  const int pmq = t & 7;           // PV decode
  const int pdq = (t >> 3) & 7;
  const int ph  = t >> 6;
  const int b  = blockIdx.x >> 8;
  const int l0 = (blockIdx.x & 255) << 2;
  const size_t qkvbase = (size_t)(b * 1024) * 768;

  const int ebase0 = (b*1024 + l0 + 2*lh) * 8192;
  const int ebase1 = ebase0 + 8192;
  const int eoff = mg2*8 + h;

  // ---- pack Q into registers (fp16 pairs over d) ----
  h2 q0[16], q1[16];
  {
    const float* qp0 = QKV + qkvbase + (size_t)(l0 + 2*lh) * 768 + h;
    const float* qp1 = qp0 + 768;
    #pragma unroll
    for (int jd = 0; jd < 16; jd++){
      q0[jd] = __builtin_amdgcn_cvt_pkrtz(qp0[jd*16], qp0[jd*16 + 8]);
      q1[jd] = __builtin_amdgcn_cvt_pkrtz(qp1[jd*16], qp1[jd*16 + 8]);
    }
  }

  float4 sf[2][4];
  float  e2[2][2];

  // ---- phase-1 prologue: K(0),K(1) + E(0),E(1) in flight ----
  stage_issue(QKV, qkvbase, 0, 256, srow, shs, sjp, sf[0]);
  stage_issue(QKV, qkvbase, 1, 256, srow, shs, sjp, sf[1]);
  e2[0][0] = E[ebase0 + eoff];
  e2[0][1] = E[ebase1 + eoff];
  e2[1][0] = E[ebase0 + KT*8 + eoff];
  e2[1][1] = E[ebase1 + KT*8 + eoff];
  stage_write(kvb, 0, srow, shs, sjp, sf[0]);
  __syncthreads();

  h2 s2[NTILE];
  float mx0 = -1e30f, mx1 = -1e30f;

  // ---- phase 1: H_hat = clip(QK^T)+E, 1 barrier/tile, depth-2 prefetch ----
  #pragma unroll
  for (int k = 0; k < NTILE; k++){
    const float e0 = e2[k&1][0], e1 = e2[k&1][1];
    if (k+2 < NTILE){
      stage_issue(QKV, qkvbase, k+2, 256, srow, shs, sjp, sf[k&1]);
      e2[k&1][0] = E[ebase0 + (k+2)*KT*8 + eoff];
      e2[k&1][1] = E[ebase1 + (k+2)*KT*8 + eoff];
    }
    if (k+1 < NTILE) stage_write(kvb, (k+1)%3, srow, shs, sjp, sf[(k+1)&1]);

    float acc0 = 0.f, acc1 = 0.f;
    const h2* kr = &kvb[((k%3)*KT + mg2)*RS + h*20];
    #pragma unroll
    for (int jw = 0; jw < 4; jw++){
      h8 kk = *(const h8*)&kr[jw*4];
      #pragma unroll
      for (int u = 0; u < 4; u++){
        h2 kj; kj[0] = kk[2*u]; kj[1] = kk[2*u+1];
        acc0 = dot2f(q0[jw*4+u], kj, acc0);
        acc1 = dot2f(q1[jw*4+u], kj, acc1);
      }
    }
    float h0 = fminf(fmaxf(acc0, -5.f), 5.f) + e0;
    float h1 = fminf(fmaxf(acc1, -5.f), 5.f) + e1;
    out[OFF_H + ebase0 + k*KT*8 + eoff] = h0;
    out[OFF_H + ebase1 + k*KT*8 + eoff] = h1;
    s2[k] = __builtin_amdgcn_cvt_pkrtz(h0, h1);
    mx0 = fmaxf(mx0, h0); mx1 = fmaxf(mx1, h1);
    __syncthreads();
  }

  // ---- phase-2 V prefetch starts now, overlaps reductions ----
  stage_issue(QKV, qkvbase, 0, 512, srow, shs, sjp, sf[0]);
  stage_issue(QKV, qkvbase, 1, 512, srow, shs, sjp, sf[1]);

  // ---- max reduce over m ----
  mx0 = fmaxf(mx0, __shfl_xor(mx0, 16)); mx0 = fmaxf(mx0, __shfl_xor(mx0, 32));
  mx1 = fmaxf(mx1, __shfl_xor(mx1, 16)); mx1 = fmaxf(mx1, __shfl_xor(mx1, 32));
  if (((t >> 4) & 3) == 0){ red[w][lh][h][0] = mx0; red[w][lh][h][1] = mx1; }
  __syncthreads();
  #pragma unroll
  for (int ww = 0; ww < 8; ww++){
    mx0 = fmaxf(mx0, red[ww][lh][h][0]);
    mx1 = fmaxf(mx1, red[ww][lh][h][1]);
  }
  __syncthreads();

  // ---- exp-sum reduce ----
  float sm0 = 0.f, sm1 = 0.f;
  #pragma unroll
  for (int k = 0; k < NTILE; k++){
    sm0 += __expf((float)s2[k][0] - mx0);
    sm1 += __expf((float)s2[k][1] - mx1);
  }
  sm0 += __shfl_xor(sm0, 16); sm0 += __shfl_xor(sm0, 32);
  sm1 += __shfl_xor(sm1, 16); sm1 += __shfl_xor(sm1, 32);
  if (((t >> 4) & 3) == 0){ red[w][lh][h][0] = sm0; red[w][lh][h][1] = sm1; }
  __syncthreads();
  float tot0 = 0.f, tot1 = 0.f;
  #pragma unroll
  for (int ww = 0; ww < 8; ww++){ tot0 += red[ww][lh][h][0]; tot1 += red[ww][lh][h][1]; }
  const float rcp0 = 1.f / tot0, rcp1 = 1.f / tot1;
  __syncthreads();

  float dg0 = 0.f, dg1 = 0.f;
  float g2r[2][2];

  // ---- phase-2 prologue: A(0) computed ahead; G(1),G(2) in flight ----
  {
    float ga0 = G[ebase0 + eoff];
    float ga1 = G[ebase1 + eoff];
    g2r[1][0] = G[ebase0 + KT*8 + eoff];
    g2r[1][1] = G[ebase1 + KT*8 + eoff];
    g2r[0][0] = G[ebase0 + 2*KT*8 + eoff];
    g2r[0][1] = G[ebase1 + 2*KT*8 + eoff];
    float sig0 = 1.f / (1.f + __expf(-ga0));
    float sig1 = 1.f / (1.f + __expf(-ga1));
    float A0 = __expf((float)s2[0][0] - mx0) * rcp0 * sig0;
    float A1 = __expf((float)s2[0][1] - mx1) * rcp1 * sig1;
    dg0 += sig0; dg1 += sig1;
    out[OFF_A + ebase0 + eoff] = A0;
    out[OFF_A + ebase1 + eoff] = A1;
    *(float2*)&at2[0][mg2][h][2*lh] = make_float2(A0, A1);
    stage_write(kvb, 0, srow, shs, sjp, sf[0]);
  }
  __syncthreads();

  float vacc[4][4] = {{0.f,0.f,0.f,0.f},{0.f,0.f,0.f,0.f},{0.f,0.f,0.f,0.f},{0.f,0.f,0.f,0.f}};

  // ---- phase 2: A(k+1) pipelined ahead of PV(k); 1 barrier/tile ----
  #pragma unroll
  for (int k = 0; k < NTILE; k++){
    if (k+2 < NTILE) stage_issue(QKV, qkvbase, k+2, 512, srow, shs, sjp, sf[k&1]);

    if (k+1 < NTILE){
      const int a = k+1;
      float ga0 = g2r[a&1][0], ga1 = g2r[a&1][1];
      if (k+3 < NTILE){
        g2r[a&1][0] = G[ebase0 + (k+3)*KT*8 + eoff];
        g2r[a&1][1] = G[ebase1 + (k+3)*KT*8 + eoff];
      }
      float sig0 = 1.f / (1.f + __expf(-ga0));
      float sig1 = 1.f / (1.f + __expf(-ga1));
      float A0 = __expf((float)s2[a][0] - mx0) * rcp0 * sig0;
      float A1 = __expf((float)s2[a][1] - mx1) * rcp1 * sig1;
      dg0 += sig0; dg1 += sig1;
      out[OFF_A + ebase0 + a*KT*8 + eoff] = A0;
      out[OFF_A + ebase1 + a*KT*8 + eoff] = A1;
      *(float2*)&at2[a&1][mg2][h][2*lh] = make_float2(A0, A1);
      stage_write(kvb, a%3, srow, shs, sjp, sf[a&1]);
    }

    // PV from V slot k%3 and at2[k&1]
    #pragma unroll
    for (int i = 0; i < 4; i++){
      const int mm = pmq + 8*i;
      h4 vv = *(const h4*)&kvb[((k%3)*KT + mm)*RS + ph*20 + 2*pdq];
      float4 aa = *(const float4*)&at2[k&1][mm][ph][0];
      float vf0 = (float)vv[0], vf1 = (float)vv[1], vf2 = (float)vv[2], vf3 = (float)vv[3];
      vacc[0][0] = fmaf(aa.x, vf0, vacc[0][0]); vacc[0][1] = fmaf(aa.x, vf1, vacc[0][1]);
      vacc[0][2] = fmaf(aa.x, vf2, vacc[0][2]); vacc[0][3] = fmaf(aa.x, vf3, vacc[0][3]);
      vacc[1][0] = fmaf(aa.y, vf0, vacc[1][0]); vacc[1][1] = fmaf(aa.y, vf1, vacc[1][1]);
      vacc[1][2] = fmaf(aa.y, vf2, vacc[1][2]); vacc[1][3] = fmaf(aa.y, vf3, vacc[1][3]);
      vacc[2][0] = fmaf(aa.z, vf0, vacc[2][0]); vacc[2][1] = fmaf(aa.z, vf1, vacc[2][1]);
      vacc[2][2] = fmaf(aa.z, vf2, vacc[2][2]); vacc[2][3] = fmaf(aa.z, vf3, vacc[2][3]);
      vacc[3][0] = fmaf(aa.w, vf0, vacc[3][0]); vacc[3][1] = fmaf(aa.w, vf1, vacc[3][1]);
      vacc[3][2] = fmaf(aa.w, vf2, vacc[3][2]); vacc[3][3] = fmaf(aa.w, vf3, vacc[3][3]);
    }
    __syncthreads();
  }

  // ---- degrees -> log1p scalers ----
  dg0 += __shfl_xor(dg0, 16); dg0 += __shfl_xor(dg0, 32);
  dg1 += __shfl_xor(dg1, 16); dg1 += __shfl_xor(dg1, 32);
  if (((t >> 4) & 3) == 0){ red[w][lh][h][0] = dg0; red[w][lh][h][1] = dg1; }
  __syncthreads();
  if (t < 16){
    float td0 = 0.f, td1 = 0.f;
    #pragma unroll
    for (int ww = 0; ww < 8; ww++){ td0 += red[ww][lh][h][0]; td1 += red[ww][lh][h][1]; }
    fin[2*lh + 0][h] = log1pf(td0);
    fin[2*lh + 1][h] = log1pf(td1);
  }
  __syncthreads();

  // ---- reduce PV over m-slices, write V_att ----
  #pragma unroll
  for (int l = 0; l < 4; l++){
    #pragma unroll
    for (int di = 0; di < 4; di++){
      float v = vacc[l][di];
      v += __shfl_xor(v, 1); v += __shfl_xor(v, 2); v += __shfl_xor(v, 4);
      vacc[l][di] = v;
    }
  }
  if (pmq == 0){
    float sc0 = fin[0][ph], sc1 = fin[1][ph], sc2 = fin[2][ph], sc3 = fin[3][ph];
    const int obase = (b*1024 + l0) * 256;
    #pragma unroll
    for (int di = 0; di < 4; di++){
      const int c = (pdq*4 + di)*8 + ph;
      out[obase +   0 + c] = vacc[0][di] * sc0;
      out[obase + 256 + c] = vacc[1][di] * sc1;
      out[obase + 512 + c] = vacc[2][di] * sc2;
      out[obase + 768 + c] = vacc[3][di] * sc3;
    }
  }
}

extern "C" void kernel_launch(void* const* d_in, const int* in_sizes, int n_in,
                              void* d_out, int out_size, void* d_ws, size_t ws_size,
                              hipStream_t stream) {
  const float* QKV = (const float*)d_in[0];
  const float* E   = (const float*)d_in[1];
  const float* G   = (const float*)d_in[2];
  float* out = (float*)d_out;
  dim3 grid(1024);
  egt_fused<<<grid, NT, 0, stream>>>(QKV, E, G, out);
}

// Round 7
// 342.619 us; speedup vs baseline: 4.5650x; 1.1927x over previous
//
#include <hip/hip_runtime.h>

#define NHEAD 8
#define NT 512
#define KT 32
#define NTILE 32
#define RS 166          // h2 (dword) stride per m-row in kv tile (8*20 + 6 pad)
#define OFF_H 1048576
#define OFF_A 34603008

typedef __fp16 h2 __attribute__((ext_vector_type(2)));
typedef __fp16 h4 __attribute__((ext_vector_type(4)));
typedef __fp16 h8 __attribute__((ext_vector_type(8)));

__device__ __forceinline__ float dot2f(h2 a, h2 b, float c){
#if __has_builtin(__builtin_amdgcn_fdot2)
  return __builtin_amdgcn_fdot2(a, b, c, false);
#else
  return fmaf((float)a[0], (float)b[0], fmaf((float)a[1], (float)b[1], c));
#endif
}

__device__ __forceinline__ void stage_issue(const float* __restrict__ QKV, size_t qkvbase,
                                            int tile, int off, int srow, int shs, int sjp,
                                            float4 sf[4]){
  const float* src = QKV + qkvbase + (size_t)(tile*KT + srow)*768 + off + sjp*32 + shs*4;
  #pragma unroll
  for (int dd = 0; dd < 4; dd++) sf[dd] = *(const float4*)(src + dd*8);
}

__device__ __forceinline__ void stage_write(h2* kvb, int slot, int srow, int shs, int sjp,
                                            const float4 sf[4]){
  #pragma unroll
  for (int hh = 0; hh < 4; hh++){
    h2 lo = __builtin_amdgcn_cvt_pkrtz(((const float*)&sf[0])[hh], ((const float*)&sf[1])[hh]);
    h2 hi = __builtin_amdgcn_cvt_pkrtz(((const float*)&sf[2])[hh], ((const float*)&sf[3])[hh]);
    h4 pk; pk[0]=lo[0]; pk[1]=lo[1]; pk[2]=hi[0]; pk[3]=hi[1];
    *(h4*)&kvb[(slot*KT + srow)*RS + (4*shs+hh)*20 + 2*sjp] = pk;
  }
}

__global__ __launch_bounds__(NT, 4) void egt_fused(
    const float* __restrict__ QKV, const float* __restrict__ E,
    const float* __restrict__ G, float* __restrict__ out)
{
  __shared__ __align__(16) h2 kvb[2*KT*RS];        // K/V ring, 2 slots (42.5 KB)
  __shared__ __align__(16) float at2[2][KT][9][4]; // A fragments, dbuf (9.2 KB)
  __shared__ float red[8][2][NHEAD][2];
  __shared__ float fin[4][NHEAD];

  const int t   = threadIdx.x;
  const int h   = t & 7;
  const int lh  = (t >> 3) & 1;
  const int mg2 = t >> 4;          // 0..31  (mapping-1: scores/E/G/A io)
  const int w   = t >> 6;
  const int srow = t >> 4;         // staging decode
  const int shs  = (t >> 3) & 1;
  const int sjp  = t & 7;
  const int pmq = t & 7;           // PV decode
  const int pdq = (t >> 3) & 7;
  const int ph  = t >> 6;
  const int b  = blockIdx.x >> 8;
  const int l0 = (blockIdx.x & 255) << 2;
  const size_t qkvbase = (size_t)(b * 1024) * 768;

  const int ebase0 = (b*1024 + l0 + 2*lh) * 8192;
  const int ebase1 = ebase0 + 8192;
  const int eoff = mg2*8 + h;

  // ---- pack Q into registers (fp16 pairs over d) ----
  h2 q0[16], q1[16];
  {
    const float* qp0 = QKV + qkvbase + (size_t)(l0 + 2*lh) * 768 + h;
    const float* qp1 = qp0 + 768;
    #pragma unroll
    for (int jd = 0; jd < 16; jd++){
      q0[jd] = __builtin_amdgcn_cvt_pkrtz(qp0[jd*16], qp0[jd*16 + 8]);
      q1[jd] = __builtin_amdgcn_cvt_pkrtz(qp1[jd*16], qp1[jd*16 + 8]);
    }
  }

  float4 sf[2][4];
  float  e2[2][2];

  // ---- phase-1 prologue: K(0),K(1) + E(0),E(1) in flight ----
  stage_issue(QKV, qkvbase, 0, 256, srow, shs, sjp, sf[0]);
  stage_issue(QKV, qkvbase, 1, 256, srow, shs, sjp, sf[1]);
  e2[0][0] = E[ebase0 + eoff];
  e2[0][1] = E[ebase1 + eoff];
  e2[1][0] = E[ebase0 + 256 + eoff];
  e2[1][1] = E[ebase1 + 256 + eoff];
  stage_write(kvb, 0, srow, shs, sjp, sf[0]);
  __syncthreads();

  float sm0 = 0.f, sm1 = 0.f;

  // ---- phase 1: H_hat = clip(QK^T)+E; no-max expsum; rolled (unroll 2) ----
  #pragma unroll 2
  for (int k = 0; k < NTILE; k++){
    const float e0 = e2[k&1][0], e1 = e2[k&1][1];
    if (k+2 < NTILE){
      stage_issue(QKV, qkvbase, k+2, 256, srow, shs, sjp, sf[k&1]);
      e2[k&1][0] = E[ebase0 + (k+2)*256 + eoff];
      e2[k&1][1] = E[ebase1 + (k+2)*256 + eoff];
    }
    if (k+1 < NTILE) stage_write(kvb, (k+1)&1, srow, shs, sjp, sf[(k+1)&1]);

    float acc0 = 0.f, acc1 = 0.f;
    const h2* kr = &kvb[((k&1)*KT + mg2)*RS + h*20];
    #pragma unroll
    for (int jw = 0; jw < 4; jw++){
      h8 kk = *(const h8*)&kr[jw*4];
      #pragma unroll
      for (int u = 0; u < 4; u++){
        h2 kj; kj[0] = kk[2*u]; kj[1] = kk[2*u+1];
        acc0 = dot2f(q0[jw*4+u], kj, acc0);
        acc1 = dot2f(q1[jw*4+u], kj, acc1);
      }
    }
    float h0 = fminf(fmaxf(acc0, -5.f), 5.f) + e0;
    float h1 = fminf(fmaxf(acc1, -5.f), 5.f) + e1;
    out[OFF_H + ebase0 + k*256 + eoff] = h0;
    out[OFF_H + ebase1 + k*256 + eoff] = h1;
    sm0 += __expf(h0);
    sm1 += __expf(h1);
    __syncthreads();
  }

  // ---- phase-2 V prefetch starts now, overlaps the sum reduction ----
  stage_issue(QKV, qkvbase, 0, 512, srow, shs, sjp, sf[0]);
  stage_issue(QKV, qkvbase, 1, 512, srow, shs, sjp, sf[1]);

  // ---- expsum reduce over m ----
  sm0 += __shfl_xor(sm0, 16); sm0 += __shfl_xor(sm0, 32);
  sm1 += __shfl_xor(sm1, 16); sm1 += __shfl_xor(sm1, 32);
  if (((t >> 4) & 3) == 0){ red[w][lh][h][0] = sm0; red[w][lh][h][1] = sm1; }
  __syncthreads();
  float tot0 = 0.f, tot1 = 0.f;
  #pragma unroll
  for (int ww = 0; ww < 8; ww++){ tot0 += red[ww][lh][h][0]; tot1 += red[ww][lh][h][1]; }
  const float rcp0 = 1.f / tot0, rcp1 = 1.f / tot1;

  // ---- phase-2 prologue: A(0) computed; G/H(1),(2) in flight ----
  float gh[2][4];
  float dg0, dg1;
  {
    float ga0 = G[ebase0 + eoff];
    float ga1 = G[ebase1 + eoff];
    float ha0 = out[OFF_H + ebase0 + eoff];
    float ha1 = out[OFF_H + ebase1 + eoff];
    gh[1][0] = G[ebase0 + 256 + eoff];
    gh[1][1] = G[ebase1 + 256 + eoff];
    gh[1][2] = out[OFF_H + ebase0 + 256 + eoff];
    gh[1][3] = out[OFF_H + ebase1 + 256 + eoff];
    gh[0][0] = G[ebase0 + 512 + eoff];
    gh[0][1] = G[ebase1 + 512 + eoff];
    gh[0][2] = out[OFF_H + ebase0 + 512 + eoff];
    gh[0][3] = out[OFF_H + ebase1 + 512 + eoff];
    float sig0 = 1.f / (1.f + __expf(-ga0));
    float sig1 = 1.f / (1.f + __expf(-ga1));
    float A0 = __expf(ha0) * rcp0 * sig0;
    float A1 = __expf(ha1) * rcp1 * sig1;
    dg0 = sig0; dg1 = sig1;
    out[OFF_A + ebase0 + eoff] = A0;
    out[OFF_A + ebase1 + eoff] = A1;
    *(float2*)&at2[0][mg2][h][2*lh] = make_float2(A0, A1);
    stage_write(kvb, 0, srow, shs, sjp, sf[0]);
  }
  __syncthreads();

  float vacc[4][4] = {{0.f,0.f,0.f,0.f},{0.f,0.f,0.f,0.f},{0.f,0.f,0.f,0.f},{0.f,0.f,0.f,0.f}};

  // ---- phase 2: A(k+1) pipelined ahead of PV(k); rolled (unroll 2) ----
  #pragma unroll 2
  for (int k = 0; k < NTILE; k++){
    if (k+2 < NTILE) stage_issue(QKV, qkvbase, k+2, 512, srow, shs, sjp, sf[k&1]);

    if (k+1 < NTILE){
      const int a = k+1;
      float ga0 = gh[a&1][0], ga1 = gh[a&1][1];
      float ha0 = gh[a&1][2], ha1 = gh[a&1][3];
      if (a+2 < NTILE){
        gh[a&1][0] = G[ebase0 + (a+2)*256 + eoff];
        gh[a&1][1] = G[ebase1 + (a+2)*256 + eoff];
        gh[a&1][2] = out[OFF_H + ebase0 + (a+2)*256 + eoff];
        gh[a&1][3] = out[OFF_H + ebase1 + (a+2)*256 + eoff];
      }
      float sig0 = 1.f / (1.f + __expf(-ga0));
      float sig1 = 1.f / (1.f + __expf(-ga1));
      float A0 = __expf(ha0) * rcp0 * sig0;
      float A1 = __expf(ha1) * rcp1 * sig1;
      dg0 += sig0; dg1 += sig1;
      out[OFF_A + ebase0 + a*256 + eoff] = A0;
      out[OFF_A + ebase1 + a*256 + eoff] = A1;
      *(float2*)&at2[a&1][mg2][h][2*lh] = make_float2(A0, A1);
      stage_write(kvb, a&1, srow, shs, sjp, sf[a&1]);
    }

    // PV from V slot k&1 and at2[k&1]
    #pragma unroll
    for (int i = 0; i < 4; i++){
      const int mm = pmq + 8*i;
      h4 vv = *(const h4*)&kvb[((k&1)*KT + mm)*RS + ph*20 + 2*pdq];
      float4 aa = *(const float4*)&at2[k&1][mm][ph][0];
      float vf0 = (float)vv[0], vf1 = (float)vv[1], vf2 = (float)vv[2], vf3 = (float)vv[3];
      vacc[0][0] = fmaf(aa.x, vf0, vacc[0][0]); vacc[0][1] = fmaf(aa.x, vf1, vacc[0][1]);
      vacc[0][2] = fmaf(aa.x, vf2, vacc[0][2]); vacc[0][3] = fmaf(aa.x, vf3, vacc[0][3]);
      vacc[1][0] = fmaf(aa.y, vf0, vacc[1][0]); vacc[1][1] = fmaf(aa.y, vf1, vacc[1][1]);
      vacc[1][2] = fmaf(aa.y, vf2, vacc[1][2]); vacc[1][3] = fmaf(aa.y, vf3, vacc[1][3]);
      vacc[2][0] = fmaf(aa.z, vf0, vacc[2][0]); vacc[2][1] = fmaf(aa.z, vf1, vacc[2][1]);
      vacc[2][2] = fmaf(aa.z, vf2, vacc[2][2]); vacc[2][3] = fmaf(aa.z, vf3, vacc[2][3]);
      vacc[3][0] = fmaf(aa.w, vf0, vacc[3][0]); vacc[3][1] = fmaf(aa.w, vf1, vacc[3][1]);
      vacc[3][2] = fmaf(aa.w, vf2, vacc[3][2]); vacc[3][3] = fmaf(aa.w, vf3, vacc[3][3]);
    }
    __syncthreads();
  }

  // ---- degrees -> log1p scalers ----
  dg0 += __shfl_xor(dg0, 16); dg0 += __shfl_xor(dg0, 32);
  dg1 += __shfl_xor(dg1, 16); dg1 += __shfl_xor(dg1, 32);
  if (((t >> 4) & 3) == 0){ red[w][lh][h][0] = dg0; red[w][lh][h][1] = dg1; }
  __syncthreads();
  if (t < 16){
    float td0 = 0.f, td1 = 0.f;
    #pragma unroll
    for (int ww = 0; ww < 8; ww++){ td0 += red[ww][lh][h][0]; td1 += red[ww][lh][h][1]; }
    fin[2*lh + 0][h] = log1pf(td0);
    fin[2*lh + 1][h] = log1pf(td1);
  }
  __syncthreads();

  // ---- reduce PV over m-slices, write V_att ----
  #pragma unroll
  for (int l = 0; l < 4; l++){
    #pragma unroll
    for (int di = 0; di < 4; di++){
      float v = vacc[l][di];
      v += __shfl_xor(v, 1); v += __shfl_xor(v, 2); v += __shfl_xor(v, 4);
      vacc[l][di] = v;
    }
  }
  if (pmq == 0){
    float sc0 = fin[0][ph], sc1 = fin[1][ph], sc2 = fin[2][ph], sc3 = fin[3][ph];
    const int obase = (b*1024 + l0) * 256;
    #pragma unroll
    for (int di = 0; di < 4; di++){
      const int c = (pdq*4 + di)*8 + ph;
      out[obase +   0 + c] = vacc[0][di] * sc0;
      out[obase + 256 + c] = vacc[1][di] * sc1;
      out[obase + 512 + c] = vacc[2][di] * sc2;
      out[obase + 768 + c] = vacc[3][di] * sc3;
    }
  }
}

extern "C" void kernel_launch(void* const* d_in, const int* in_sizes, int n_in,
                              void* d_out, int out_size, void* d_ws, size_t ws_size,
                              hipStream_t stream) {
  const float* QKV = (const float*)d_in[0];
  const float* E   = (const float*)d_in[1];
  const float* G   = (const float*)d_in[2];
  float* out = (float*)d_out;
  dim3 grid(1024);
  egt_fused<<<grid, NT, 0, stream>>>(QKV, E, G, out);
}